// Round 1
// baseline (292.463 us; speedup 1.0000x reference)
//
#include <hip/hip_runtime.h>
#include <cstdint>

#define NN 50000
#define NE 600000
#define DD 128
#define ROWS 32

// ws layout: counts[NN] | gcount[16] | offsets[NN] | cursor[NN] | srcs[NE]

// ---------------------------------------------------------------------------
// Kernel 1: histogram of dst degrees + fused edge_index[1] float cast
// ---------------------------------------------------------------------------
__global__ __launch_bounds__(256) void hist_kernel(
    const int* __restrict__ ei, int* __restrict__ counts,
    float* __restrict__ oe)
{
    int e = blockIdx.x * 256 + threadIdx.x;
    if (e < NE) {
        int dst = ei[NE + e];
        atomicAdd(&counts[dst], 1);
        oe[NE + e] = (float)dst;   // fused eidx passthrough (dst half)
    }
}

// ---------------------------------------------------------------------------
// Kernel 2: segment-offset assignment. Node-order of segments is irrelevant
// (finish only needs per-node contiguity), so replace the 3-stage prefix
// scan with per-wave scan + one global atomicAdd per wave (784 atomics).
// ---------------------------------------------------------------------------
__global__ __launch_bounds__(256) void assign_kernel(
    const int* __restrict__ counts, int* __restrict__ gcount,
    int* __restrict__ offsets, int* __restrict__ cursor)
{
    const int t = blockIdx.x * 256 + threadIdx.x;
    const int ln = threadIdx.x & 63;
    int c = (t < NN) ? counts[t] : 0;
    int s = c;
    #pragma unroll
    for (int d = 1; d < 64; d <<= 1) {   // inclusive wave scan
        int n = __shfl_up(s, d, 64);
        if (ln >= d) s += n;
    }
    int total = __shfl(s, 63, 64);
    int base = 0;
    if (ln == 0) base = atomicAdd(gcount, total);
    base = __shfl(base, 0, 64);
    if (t < NN) {
        int off = base + s - c;          // exclusive within wave + wave base
        offsets[t] = off;
        cursor[t]  = off;
    }
}

// ---------------------------------------------------------------------------
// Kernel 3: counting-sort edges by dst + fused edge_index[0] float cast
// ---------------------------------------------------------------------------
__global__ __launch_bounds__(256) void reorder_kernel(
    const int* __restrict__ ei, int* __restrict__ cursor,
    int* __restrict__ srcs, float* __restrict__ oe)
{
    int e = blockIdx.x * 256 + threadIdx.x;
    if (e < NE) {
        int src = ei[e];
        int dst = ei[NE + e];
        int p = atomicAdd(&cursor[dst], 1);
        srcs[p] = src;
        oe[e] = (float)src;   // fused eidx passthrough (src half)
    }
}

// ---------------------------------------------------------------------------
// Kernel 4 (fused): gather-mean into LDS, then
// out = ELU( agg @ W_l^T + b_l + x @ W_r^T ), f32 store.
// 512 threads/block (8 waves): LDS 33.3 KB -> 4 blocks/CU -> 32 waves/CU
// (vs 16 before). Each wave gathers 4 nodes instead of 8 -> 2x concurrent
// gather chains; 2x waves to overlap GEMM VALU with gather latency.
// ---------------------------------------------------------------------------
__global__ __launch_bounds__(512, 8) void finish_kernel(
    const int* __restrict__ offsets, const int* __restrict__ counts,
    const int* __restrict__ srcs, const float* __restrict__ x,
    const float* __restrict__ W_l, const float* __restrict__ b_l,
    const float* __restrict__ W_r, float* __restrict__ out)
{
    __shared__ float As[ROWS][260];
    const int row0 = blockIdx.x * ROWS;
    const int t = threadIdx.x;
    const int wv = t >> 6;     // 0..7
    const int ln = t & 63;

    // stage x rows (cols 128..255 of the tile), coalesced
    for (int i = t; i < ROWS * DD; i += 512) {
        int r = i >> 7, k = i & 127;
        int row = row0 + r;
        As[r][DD + k] = (row < NN) ? x[(size_t)row * DD + k] : 0.f;
    }

    // gather-mean agg rows (cols 0..127); one wave per 4 nodes
    for (int rr = 0; rr < 4; rr++) {
        int r = wv * 4 + rr;
        int node = row0 + r;
        float a0x = 0.f, a0y = 0.f, a1x = 0.f, a1y = 0.f;
        float a2x = 0.f, a2y = 0.f, a3x = 0.f, a3y = 0.f;
        float scale = 0.f;
        if (node < NN) {   // wave-uniform branch
            int beg = __builtin_amdgcn_readfirstlane(offsets[node]);
            int cnt = __builtin_amdgcn_readfirstlane(counts[node]);
            int e = beg, end = beg + cnt;
            for (; e + 4 <= end; e += 4) {
                int s0 = srcs[e], s1 = srcs[e + 1];
                int s2 = srcs[e + 2], s3 = srcs[e + 3];
                float2 v0 = *reinterpret_cast<const float2*>(x + (size_t)s0 * DD + 2 * ln);
                float2 v1 = *reinterpret_cast<const float2*>(x + (size_t)s1 * DD + 2 * ln);
                float2 v2 = *reinterpret_cast<const float2*>(x + (size_t)s2 * DD + 2 * ln);
                float2 v3 = *reinterpret_cast<const float2*>(x + (size_t)s3 * DD + 2 * ln);
                a0x += v0.x; a0y += v0.y;
                a1x += v1.x; a1y += v1.y;
                a2x += v2.x; a2y += v2.y;
                a3x += v3.x; a3y += v3.y;
            }
            for (; e < end; e++) {
                int s0 = srcs[e];
                float2 v0 = *reinterpret_cast<const float2*>(x + (size_t)s0 * DD + 2 * ln);
                a0x += v0.x; a0y += v0.y;
            }
            scale = 1.0f / fmaxf((float)cnt, 1.0f);
        }
        float2 st;
        st.x = (a0x + a1x + a2x + a3x) * scale;
        st.y = (a0y + a1y + a2y + a3y) * scale;
        *reinterpret_cast<float2*>(&As[r][2 * ln]) = st;
    }
    __syncthreads();

    // GEMM: 512 threads -> 8 outputs each: rows {rg, rg+16}, cols c0..c0+3
    const int rg = t & 15;
    const int cg = t >> 4;     // 0..31
    const int c0 = cg * 4;

    float acc[2][4];
    #pragma unroll
    for (int i = 0; i < 2; i++)
        #pragma unroll
        for (int j = 0; j < 4; j++) acc[i][j] = 0.f;

    // phase 1: agg @ W_l^T
    for (int k = 0; k < DD; k += 4) {
        float4 av[2], wvv[4];
        av[0] = *reinterpret_cast<const float4*>(&As[rg][k]);
        av[1] = *reinterpret_cast<const float4*>(&As[rg + 16][k]);
        #pragma unroll
        for (int j = 0; j < 4; j++)
            wvv[j] = *reinterpret_cast<const float4*>(W_l + (size_t)(c0 + j) * DD + k);
        #pragma unroll
        for (int i = 0; i < 2; i++)
            #pragma unroll
            for (int j = 0; j < 4; j++)
                acc[i][j] += av[i].x * wvv[j].x + av[i].y * wvv[j].y +
                             av[i].z * wvv[j].z + av[i].w * wvv[j].w;
    }
    // phase 2: x @ W_r^T
    for (int k = 0; k < DD; k += 4) {
        float4 av[2], wvv[4];
        av[0] = *reinterpret_cast<const float4*>(&As[rg][DD + k]);
        av[1] = *reinterpret_cast<const float4*>(&As[rg + 16][DD + k]);
        #pragma unroll
        for (int j = 0; j < 4; j++)
            wvv[j] = *reinterpret_cast<const float4*>(W_r + (size_t)(c0 + j) * DD + k);
        #pragma unroll
        for (int i = 0; i < 2; i++)
            #pragma unroll
            for (int j = 0; j < 4; j++)
                acc[i][j] += av[i].x * wvv[j].x + av[i].y * wvv[j].y +
                             av[i].z * wvv[j].z + av[i].w * wvv[j].w;
    }

    // epilogue: + b_l, ELU, f32 float4 store
    const float4 bv = *reinterpret_cast<const float4*>(b_l + c0);
    #pragma unroll
    for (int i = 0; i < 2; i++) {
        int row = row0 + rg + 16 * i;
        if (row < NN) {
            float4 o;
            o.x = acc[i][0] + bv.x;
            o.y = acc[i][1] + bv.y;
            o.z = acc[i][2] + bv.z;
            o.w = acc[i][3] + bv.w;
            o.x = o.x > 0.f ? o.x : expm1f(o.x);
            o.y = o.y > 0.f ? o.y : expm1f(o.y);
            o.z = o.z > 0.f ? o.z : expm1f(o.z);
            o.w = o.w > 0.f ? o.w : expm1f(o.w);
            *reinterpret_cast<float4*>(out + (size_t)row * DD + c0) = o;
        }
    }
}

extern "C" void kernel_launch(void* const* d_in, const int* in_sizes, int n_in,
                              void* d_out, int out_size, void* d_ws, size_t ws_size,
                              hipStream_t stream)
{
    const float* x   = (const float*)d_in[0];
    const int*   ei  = (const int*)d_in[1];
    const float* W_l = (const float*)d_in[2];
    const float* b_l = (const float*)d_in[3];
    const float* W_r = (const float*)d_in[4];
    float* out = (float*)d_out;
    float* oe  = out + (size_t)NN * DD;   // edge_index-as-float output

    int* counts  = (int*)d_ws;
    int* gcount  = counts + NN;           // 16-int pad, only [0] used
    int* offsets = gcount + 16;
    int* cursor  = offsets + NN;
    int* srcs    = cursor + NN;

    // counts + gcount must be zero each launch (ws re-poisoned to 0xAA)
    (void)hipMemsetAsync(counts, 0, (size_t)(NN + 16) * sizeof(int), stream);

    int eb = (NE + 255) / 256;
    hist_kernel<<<eb, 256, 0, stream>>>(ei, counts, oe);

    int ab = (NN + 255) / 256;
    assign_kernel<<<ab, 256, 0, stream>>>(counts, gcount, offsets, cursor);

    reorder_kernel<<<eb, 256, 0, stream>>>(ei, cursor, srcs, oe);

    int fb = (NN + ROWS - 1) / ROWS;
    finish_kernel<<<fb, 512, 0, stream>>>(offsets, counts, srcs, x,
                                          W_l, b_l, W_r, out);
}

// Round 2
// 250.064 us; speedup vs baseline: 1.1696x; 1.1696x over previous
//
#include <hip/hip_runtime.h>
#include <cstdint>

#define NN 50000
#define NE 600000
#define DD 128
#define ROWS 32

// ws layout: counts[NN] | gcount[16] | offsets[NN] | cursor[NN] | srcs[NE]

// ---------------------------------------------------------------------------
// Kernel 1: histogram of dst degrees + fused edge_index[1] float cast.
// 4 edges/thread via int4 (NE % 4 == 0).
// ---------------------------------------------------------------------------
__global__ __launch_bounds__(256) void hist_kernel(
    const int* __restrict__ ei, int* __restrict__ counts,
    float* __restrict__ oe)
{
    int e4 = (blockIdx.x * 256 + threadIdx.x) * 4;
    if (e4 + 4 <= NE) {
        int4 d = *reinterpret_cast<const int4*>(ei + NE + e4);
        atomicAdd(&counts[d.x], 1);
        atomicAdd(&counts[d.y], 1);
        atomicAdd(&counts[d.z], 1);
        atomicAdd(&counts[d.w], 1);
        float4 f;
        f.x = (float)d.x; f.y = (float)d.y; f.z = (float)d.z; f.w = (float)d.w;
        *reinterpret_cast<float4*>(oe + NE + e4) = f;
    }
}

// ---------------------------------------------------------------------------
// Kernel 2: segment-offset assignment (per-wave scan + one atomic per wave).
// Segment order is wave-granular: nodes [w*64,(w+1)*64) get a contiguous
// ascending range -> any aligned 32-node window is contiguous in srcs.
// ---------------------------------------------------------------------------
__global__ __launch_bounds__(256) void assign_kernel(
    const int* __restrict__ counts, int* __restrict__ gcount,
    int* __restrict__ offsets, int* __restrict__ cursor)
{
    const int t = blockIdx.x * 256 + threadIdx.x;
    const int ln = threadIdx.x & 63;
    int c = (t < NN) ? counts[t] : 0;
    int s = c;
    #pragma unroll
    for (int d = 1; d < 64; d <<= 1) {   // inclusive wave scan
        int n = __shfl_up(s, d, 64);
        if (ln >= d) s += n;
    }
    int total = __shfl(s, 63, 64);
    int base = 0;
    if (ln == 0) base = atomicAdd(gcount, total);
    base = __shfl(base, 0, 64);
    if (t < NN) {
        int off = base + s - c;          // exclusive within wave + wave base
        offsets[t] = off;
        cursor[t]  = off;
    }
}

// ---------------------------------------------------------------------------
// Kernel 3: counting-sort edges by dst + fused edge_index[0] float cast.
// 4 edges/thread via int4.
// ---------------------------------------------------------------------------
__global__ __launch_bounds__(256) void reorder_kernel(
    const int* __restrict__ ei, int* __restrict__ cursor,
    int* __restrict__ srcs, float* __restrict__ oe)
{
    int e4 = (blockIdx.x * 256 + threadIdx.x) * 4;
    if (e4 + 4 <= NE) {
        int4 sv = *reinterpret_cast<const int4*>(ei + e4);
        int4 dv = *reinterpret_cast<const int4*>(ei + NE + e4);
        int p0 = atomicAdd(&cursor[dv.x], 1);
        int p1 = atomicAdd(&cursor[dv.y], 1);
        int p2 = atomicAdd(&cursor[dv.z], 1);
        int p3 = atomicAdd(&cursor[dv.w], 1);
        srcs[p0] = sv.x; srcs[p1] = sv.y; srcs[p2] = sv.z; srcs[p3] = sv.w;
        float4 f;
        f.x = (float)sv.x; f.y = (float)sv.y; f.z = (float)sv.z; f.w = (float)sv.w;
        *reinterpret_cast<float4*>(oe + e4) = f;
    }
}

// ---------------------------------------------------------------------------
// Kernel 4 (fused): gather-mean into LDS, then
// out = ELU( agg @ W_l^T + b_l + x @ W_r^T ), f32 store.
// Gather redesign (MLP-bound, not TLP-bound — r1 lesson):
//  - per-node index list preloaded with ONE coalesced load into lane regs;
//    inner loop gets indices via __shfl (no L2 round-trip in the chain)
//  - paired-row float4 loads: half-wave per edge row, 8 edges (4 KB) in
//    flight per iteration, half the load instructions of the float2 scheme
// 256 thr, VGPR cap 128 (launch_bounds(256,4)); LDS 33.3 KB -> 4 blocks/CU.
// ---------------------------------------------------------------------------
__global__ __launch_bounds__(256, 4) void finish_kernel(
    const int* __restrict__ offsets, const int* __restrict__ counts,
    const int* __restrict__ srcs, const float* __restrict__ x,
    const float* __restrict__ W_l, const float* __restrict__ b_l,
    const float* __restrict__ W_r, float* __restrict__ out)
{
    __shared__ float As[ROWS][260];
    const int row0 = blockIdx.x * ROWS;
    const int t = threadIdx.x;
    const int wv = t >> 6;       // 0..3
    const int ln = t & 63;
    const int h  = ln >> 5;      // half-wave: which edge of a pair
    const int cc = (ln & 31) * 4; // column base for gather loads

    // stage x rows (cols 128..255 of the tile), float4 coalesced
    for (int i = t; i < ROWS * DD / 4; i += 256) {
        int r = i >> 5, k4 = (i & 31) * 4;
        int row = row0 + r;
        float4 v = make_float4(0.f, 0.f, 0.f, 0.f);
        if (row < NN) v = *reinterpret_cast<const float4*>(x + (size_t)row * DD + k4);
        *reinterpret_cast<float4*>(&As[r][DD + k4]) = v;
    }

    // batch-load beg/cnt for this wave's 8 nodes into lanes 0..7
    int nodeL = row0 + wv * 8 + (ln & 7);
    int begL = 0, cntL = 0;
    if (nodeL < NN) { begL = offsets[nodeL]; cntL = counts[nodeL]; }

    // gather-mean agg rows (cols 0..127); one wave per 8 nodes
    for (int rr = 0; rr < 8; rr++) {
        int r = wv * 8 + rr;
        int node = row0 + r;
        float4 acc0 = make_float4(0.f, 0.f, 0.f, 0.f);
        float4 acc1 = make_float4(0.f, 0.f, 0.f, 0.f);
        float sc = 0.f;
        if (node < NN) {   // wave-uniform branch
            int beg = __shfl(begL, rr, 64);
            int cnt = __shfl(cntL, rr, 64);
            int lim = cnt < 64 ? cnt : 64;
            // one coalesced load grabs the whole index list into lane regs
            int myidx = 0;
            if (ln < lim) myidx = srcs[beg + ln];
            int e = 0;
            for (; e + 8 <= lim; e += 8) {
                int s0 = __shfl(myidx, e + 0 + h, 64);
                int s1 = __shfl(myidx, e + 2 + h, 64);
                int s2 = __shfl(myidx, e + 4 + h, 64);
                int s3 = __shfl(myidx, e + 6 + h, 64);
                float4 v0 = *reinterpret_cast<const float4*>(x + (size_t)s0 * DD + cc);
                float4 v1 = *reinterpret_cast<const float4*>(x + (size_t)s1 * DD + cc);
                float4 v2 = *reinterpret_cast<const float4*>(x + (size_t)s2 * DD + cc);
                float4 v3 = *reinterpret_cast<const float4*>(x + (size_t)s3 * DD + cc);
                acc0.x += v0.x; acc0.y += v0.y; acc0.z += v0.z; acc0.w += v0.w;
                acc1.x += v1.x; acc1.y += v1.y; acc1.z += v1.z; acc1.w += v1.w;
                acc0.x += v2.x; acc0.y += v2.y; acc0.z += v2.z; acc0.w += v2.w;
                acc1.x += v3.x; acc1.y += v3.y; acc1.z += v3.z; acc1.w += v3.w;
            }
            for (; e + 2 <= lim; e += 2) {
                int s0 = __shfl(myidx, e + h, 64);
                float4 v0 = *reinterpret_cast<const float4*>(x + (size_t)s0 * DD + cc);
                acc0.x += v0.x; acc0.y += v0.y; acc0.z += v0.z; acc0.w += v0.w;
            }
            if (e < lim) {   // odd leftover: both halves load, half h==0 adds
                int s0 = __shfl(myidx, e, 64);
                float4 v0 = *reinterpret_cast<const float4*>(x + (size_t)s0 * DD + cc);
                if (h == 0) {
                    acc0.x += v0.x; acc0.y += v0.y; acc0.z += v0.z; acc0.w += v0.w;
                }
            }
            // safety net: degree > 64 (never hit for Poisson(12) data)
            for (int e2 = 64; e2 < cnt; e2++) {
                int s0 = srcs[beg + e2];
                float4 v0 = *reinterpret_cast<const float4*>(x + (size_t)s0 * DD + cc);
                if (h == 0) {
                    acc0.x += v0.x; acc0.y += v0.y; acc0.z += v0.z; acc0.w += v0.w;
                }
            }
            sc = 1.0f / fmaxf((float)cnt, 1.0f);
        }
        // combine the two edge-subset halves, then cross-half add
        float4 s4;
        s4.x = acc0.x + acc1.x; s4.y = acc0.y + acc1.y;
        s4.z = acc0.z + acc1.z; s4.w = acc0.w + acc1.w;
        s4.x += __shfl_xor(s4.x, 32, 64);
        s4.y += __shfl_xor(s4.y, 32, 64);
        s4.z += __shfl_xor(s4.z, 32, 64);
        s4.w += __shfl_xor(s4.w, 32, 64);
        if (h == 0) {
            float4 st;
            st.x = s4.x * sc; st.y = s4.y * sc;
            st.z = s4.z * sc; st.w = s4.w * sc;
            *reinterpret_cast<float4*>(&As[r][cc]) = st;
        }
    }
    __syncthreads();

    // GEMM: 256 threads -> 16 outputs each: rows {rg,+8,+16,+24}, cols c0..c0+3
    const int rg = t & 7;
    const int cg = t >> 3;
    const int c0 = cg * 4;

    float acc[4][4];
    #pragma unroll
    for (int i = 0; i < 4; i++)
        #pragma unroll
        for (int j = 0; j < 4; j++) acc[i][j] = 0.f;

    // phase 1: agg @ W_l^T
    for (int k = 0; k < DD; k += 4) {
        float4 av[4], wvv[4];
        #pragma unroll
        for (int i = 0; i < 4; i++)
            av[i] = *reinterpret_cast<const float4*>(&As[rg + 8 * i][k]);
        #pragma unroll
        for (int j = 0; j < 4; j++)
            wvv[j] = *reinterpret_cast<const float4*>(W_l + (size_t)(c0 + j) * DD + k);
        #pragma unroll
        for (int i = 0; i < 4; i++)
            #pragma unroll
            for (int j = 0; j < 4; j++)
                acc[i][j] += av[i].x * wvv[j].x + av[i].y * wvv[j].y +
                             av[i].z * wvv[j].z + av[i].w * wvv[j].w;
    }
    // phase 2: x @ W_r^T
    for (int k = 0; k < DD; k += 4) {
        float4 av[4], wvv[4];
        #pragma unroll
        for (int i = 0; i < 4; i++)
            av[i] = *reinterpret_cast<const float4*>(&As[rg + 8 * i][DD + k]);
        #pragma unroll
        for (int j = 0; j < 4; j++)
            wvv[j] = *reinterpret_cast<const float4*>(W_r + (size_t)(c0 + j) * DD + k);
        #pragma unroll
        for (int i = 0; i < 4; i++)
            #pragma unroll
            for (int j = 0; j < 4; j++)
                acc[i][j] += av[i].x * wvv[j].x + av[i].y * wvv[j].y +
                             av[i].z * wvv[j].z + av[i].w * wvv[j].w;
    }

    // epilogue: + b_l, ELU, f32 float4 store
    const float4 bv = *reinterpret_cast<const float4*>(b_l + c0);
    #pragma unroll
    for (int i = 0; i < 4; i++) {
        int row = row0 + rg + 8 * i;
        if (row < NN) {
            float4 o;
            o.x = acc[i][0] + bv.x;
            o.y = acc[i][1] + bv.y;
            o.z = acc[i][2] + bv.z;
            o.w = acc[i][3] + bv.w;
            o.x = o.x > 0.f ? o.x : expm1f(o.x);
            o.y = o.y > 0.f ? o.y : expm1f(o.y);
            o.z = o.z > 0.f ? o.z : expm1f(o.z);
            o.w = o.w > 0.f ? o.w : expm1f(o.w);
            *reinterpret_cast<float4*>(out + (size_t)row * DD + c0) = o;
        }
    }
}

extern "C" void kernel_launch(void* const* d_in, const int* in_sizes, int n_in,
                              void* d_out, int out_size, void* d_ws, size_t ws_size,
                              hipStream_t stream)
{
    const float* x   = (const float*)d_in[0];
    const int*   ei  = (const int*)d_in[1];
    const float* W_l = (const float*)d_in[2];
    const float* b_l = (const float*)d_in[3];
    const float* W_r = (const float*)d_in[4];
    float* out = (float*)d_out;
    float* oe  = out + (size_t)NN * DD;   // edge_index-as-float output

    int* counts  = (int*)d_ws;
    int* gcount  = counts + NN;           // 16-int pad, only [0] used
    int* offsets = gcount + 16;
    int* cursor  = offsets + NN;
    int* srcs    = cursor + NN;

    // counts + gcount must be zero each launch (ws re-poisoned to 0xAA)
    (void)hipMemsetAsync(counts, 0, (size_t)(NN + 16) * sizeof(int), stream);

    int eb4 = (NE / 4 + 255) / 256;
    hist_kernel<<<eb4, 256, 0, stream>>>(ei, counts, oe);

    int ab = (NN + 255) / 256;
    assign_kernel<<<ab, 256, 0, stream>>>(counts, gcount, offsets, cursor);

    reorder_kernel<<<eb4, 256, 0, stream>>>(ei, cursor, srcs, oe);

    int fb = (NN + ROWS - 1) / ROWS;
    finish_kernel<<<fb, 256, 0, stream>>>(offsets, counts, srcs, x,
                                          W_l, b_l, W_r, out);
}